// Round 16
// baseline (103.836 us; speedup 1.0000x reference)
//
#include <hip/hip_runtime.h>

// out[n, mu, mup] = sum_{(m1,m2)∈T(mu)} sum_{(m1p,m2p)∈T(mup)}
//     c_p*c_q * X1[n,m1,m1p] * X2[n,m2,m2p],   T(mu)={m1+m2==mu+4}
// Rank-1 weights: sp*w0[q] = c_p*c_q, w0[q]=mult[q], sp=csh[p]=mult[p]/mult[0].
//
// R16 = R15 (tied best, ~23us) restructured for MAX OCCUPANCY. Evidence:
// time scales ~1/waves-per-CU (R12: 27->18 waves = +43% time); all
// instruction-count levers (R12-R15) were neutral -> TLP/latency-bound.
// Current shape caps at 3 blk x 9 waves = 27 of the 32-wave HW cap. Change:
//  - NT=512 (8 waves), NB=60 -> LDS 2 x 19KiB arrays + csh = 39.2 KB
//    -> 4 blocks/CU x 8 waves = 32 waves/CU (+18.5%).
//  - wave w -> mu=w; wave 0 runs mu=8 as a 2nd pass (5+5 pairs ~ wave4's 9).
//  - lanes 60..63: clamped LDS base (no OOB), stores guarded (6% waste).
// Else R15-verbatim: linear [n][81] LDS (stride 81 odd -> 2-way free),
// global_load_lds x16 staging, SGPR w0 (const-indexed ONLY, inline, never
// passed/addressed — R6/R8/R11 scratch rules), csh LDS table, direct stores.

namespace {

struct QTab {
  int m1p[61];
  int m2p[61];
  int mup[61];
  constexpr QTab() : m1p{}, m2p{}, mup{} {
    int idx = 0;
    for (int mu = 0; mu < 9; ++mu)
      for (int a = 0; a < 9; ++a) {
        int b = mu + 4 - a;
        if (b >= 0 && b < 9) {
          m1p[idx] = a; m2p[idx] = b; mup[idx] = mu; ++idx;
        }
      }
  }
};
constexpr QTab QT{};

}  // namespace

// pairs per mu: [5,6,7,8,9,8,7,6,5]; prefix = first pair index of each mu
__constant__ __device__ int kPrefix[9] = {0, 5, 11, 18, 26, 35, 43, 50, 56};

__device__ __forceinline__ float uniform_f32(float v) {
  return __int_as_float(__builtin_amdgcn_readfirstlane(__float_as_int(v)));
}

typedef unsigned int u32;

// Async global->LDS DMA, width 16: LDS dest = uniform base + lane*16.
__device__ __forceinline__ void glds16(const float* g, float* lds) {
  __builtin_amdgcn_global_load_lds(
      (const __attribute__((address_space(1))) u32*)g,
      (__attribute__((address_space(3))) u32*)(u32)(uintptr_t)lds, 16, 0, 0);
}

#define NB 60            // n per block
#define NT 512           // threads = 8 waves
#define ADW (NB * 81)    // 4860 dwords needed per array per block
#define CH 256           // dwords per x16 wave-chunk (64 lanes * 4 dw)
#define NCH 19           // chunks per array (19*256 = 4864 >= 4860)
#define LDW (NCH * CH)   // 4864 dwords LDS per array

// Full compute + store for one mu value (wave-uniform). Uses in-scope
// lx1/lx2/csh/w0/act/nglob/out. Macro (not function): w0 must never be
// passed by reference or SROA dies -> scratch (R11 lesson).
#define COMPUTE_MU(MUV)                                                       \
  {                                                                           \
    const int mu_c = (MUV);                                                   \
    const int m1lo_c = (mu_c - 4 > 0) ? mu_c - 4 : 0;                         \
    const int pbase_c = kPrefix[mu_c];                                        \
    float acc[9];                                                             \
    _Pragma("unroll") for (int j = 0; j < 9; ++j) acc[j] = 0.0f;              \
    _Pragma("unroll") for (int m1 = 0; m1 < 9; ++m1) {                        \
      const int m2 = mu_c + 4 - m1;    /* wave-uniform scalar */              \
      if (m2 >= 0 && m2 <= 8) {        /* uniform guard */                    \
        const int p = pbase_c + (m1 - m1lo_c);                                \
        const float sp = csh[p];       /* uniform ds_read broadcast */        \
        float x1w[9], x2r[9];                                                 \
        _Pragma("unroll") for (int j = 0; j < 9; ++j)                         \
            x1w[j] = lx1[m1 * 9 + j] * sp;                                    \
        _Pragma("unroll") for (int j = 0; j < 9; ++j)                         \
            x2r[j] = lx2[m2 * 9 + j];                                         \
        _Pragma("unroll") for (int q = 0; q < 61; ++q)                        \
            acc[QT.mup[q]] = fmaf(w0[q], x1w[QT.m1p[q]] * x2r[QT.m2p[q]],     \
                                  acc[QT.mup[q]]);                            \
      }                                                                       \
    }                                                                         \
    if (act) {                                                                \
      float* __restrict__ op = out + nglob * 81 + mu_c * 9;                   \
      _Pragma("unroll") for (int j = 0; j < 9; ++j) op[j] = acc[j];           \
    }                                                                         \
  }

__global__ __launch_bounds__(NT)
void wigner_combine_kernel(const float* __restrict__ X1,
                           const float* __restrict__ X2,
                           const float* __restrict__ mult,
                           float* __restrict__ out, int N) {
  __shared__ __align__(16) float x1s[LDW];  // 19456 B, linear [n][81]
  __shared__ __align__(16) float x2s[LDW];  // 19456 B
  __shared__ float csh[61];                 // per-pair scales c_p/c_p0

  const int t = threadIdx.x;
  const int w = t >> 6;      // wave id 0..7
  const int lane = t & 63;
  const long gbase = (long)blockIdx.x * ADW;  // dword base of this block
  const long totaldw = (long)N * 81;

  // ---- weight row 0 -> 61 SGPRs (inline, constant indices ONLY) ----
  float w0[61];
#pragma unroll
  for (int q = 0; q < 61; ++q) w0[q] = uniform_f32(mult[q]);

  if (t < 61) csh[t] = mult[t] * (1.0f / mult[0]);

  // ---- stage: async linear DMA, 38 x16 chunks over 8 waves ----
#pragma unroll
  for (int k = 0; k < 5; ++k) {
    const int i = w + 8 * k;  // wave-uniform chunk id, 0..39
    if (i < 2 * NCH) {
      const int ci = (i < NCH) ? i : i - NCH;
      const int cbase = ci * CH;
      const float* gsrc = ((i < NCH) ? X1 : X2) + gbase + cbase + lane * 4;
      float* ldst = ((i < NCH) ? x1s : x2s) + cbase;
      if (gbase + cbase + lane * 4 < totaldw) glds16(gsrc, ldst);
    }
  }
  __syncthreads();  // vmcnt(0) drains the DMA

  // ---- compute: wave = mu (wave 0 also does mu=8), lane = local n ----
  const int mu0 = __builtin_amdgcn_readfirstlane(w);  // wave-uniform
  const long nglob = (long)blockIdx.x * NB + lane;
  const bool act = (lane < NB) && (nglob < N);
  const int ln = (lane < NB) ? lane : 0;  // clamp: no OOB LDS reads
  const float* __restrict__ lx1 = x1s + ln * 81;
  const float* __restrict__ lx2 = x2s + ln * 81;

  COMPUTE_MU(mu0);
  if (mu0 == 0) COMPUTE_MU(8);  // wave 0: second pass (5+5 pairs, balanced)
}

extern "C" void kernel_launch(void* const* d_in, const int* in_sizes, int n_in,
                              void* d_out, int out_size, void* d_ws, size_t ws_size,
                              hipStream_t stream) {
  const float* X1 = (const float*)d_in[0];
  const float* X2 = (const float*)d_in[1];
  const float* mult = (const float*)d_in[6];
  float* out = (float*)d_out;

  const int N = in_sizes[0] / 81;
  const int blocks = (N + NB - 1) / NB;
  wigner_combine_kernel<<<blocks, NT, 0, stream>>>(X1, X2, mult, out, N);
}